// Round 9
// baseline (829.146 us; speedup 1.0000x reference)
//
#include <hip/hip_runtime.h>
#include <math.h>

#define NN 50000
#define NE 800000

typedef float f32x4 __attribute__((ext_vector_type(4)));
typedef short s16x8 __attribute__((ext_vector_type(8)));
typedef unsigned int u32;

__device__ __forceinline__ short f2bf(float f) {
    union { float f; u32 u; } v; v.f = f;
    u32 u = v.u;
    u += 0x7FFF + ((u >> 16) & 1);   // round-to-nearest-even
    return (short)(u >> 16);
}

__device__ __forceinline__ s16x8 cvt8(f32x4 a, f32x4 b) {
    s16x8 r;
    r[0] = f2bf(a[0]); r[1] = f2bf(a[1]); r[2] = f2bf(a[2]); r[3] = f2bf(a[3]);
    r[4] = f2bf(b[0]); r[5] = f2bf(b[1]); r[6] = f2bf(b[2]); r[7] = f2bf(b[3]);
    return r;
}

__device__ __forceinline__ float gelu_exact(float x) {
    return 0.5f * x * (1.0f + erff(x * 0.70710678118654752f));
}

// tanh-form GELU (certified r8): max dev vs erf-GELU ~3e-3 on h -> <2e-3 on out.
__device__ __forceinline__ float gelu_fast(float x) {
    const float z = 1.5957691216f * x * (1.0f + 0.044715f * x * x);
    return x * __builtin_amdgcn_rcpf(1.0f + __expf(-z));
}

// ---- prep: transpose-convert edge weights to bf16 [col][k] ----
__global__ __launch_bounds__(256) void prep_e(
    const float* __restrict__ ew1, const float* __restrict__ ew2,
    short* __restrict__ ew1t, short* __restrict__ ew2t)
{
    int idx = blockIdx.x * 256 + threadIdx.x;
    if (idx < 24576) {                       // e_w1 [192][128] -> [128][192]
        int k = idx >> 7, c = idx & 127;
        ew1t[c * 192 + k] = f2bf(ew1[idx]);
    } else if (idx < 32768) {                // e_w2 [128][64] -> [64][128]
        int i = idx - 24576; int k = i >> 6, c = i & 63;
        ew2t[c * 128 + k] = f2bf(ew2[i]);
    }
}

// ---- edge kernel (certified r8 dataflow; aggregation path templated) ----
// SLOTS=1: record edge row id per dst node (1 one-lane atomic/row, 800k total)
// SLOTS=0: certified r8 full-atomic agg fallback (52M atomics)
template<bool SLOTS>
__global__ __launch_bounds__(256) void edge_k(
    const float* __restrict__ nf, const int* __restrict__ ei,
    const float* __restrict__ ef,
    const short* __restrict__ w1t, const float* __restrict__ b1,
    const short* __restrict__ w2t, const float* __restrict__ b2,
    const float* __restrict__ gamma, const float* __restrict__ beta,
    float* __restrict__ eout, float* __restrict__ agg,
    int* __restrict__ cnti, u32* __restrict__ slots)
{
    __shared__ short h_lds[128][128];        // 32768 B; aliased float[128][64]
    const int tid  = threadIdx.x;
    const int wave = tid >> 6, lane = tid & 63;
    const int lo = lane & 15, hi = lane >> 4;
    const int eb = blockIdx.x * 128 + wave * 32;

    const int ar0 = eb + lo, ar1 = eb + 16 + lo;
    const int s0 = ei[ar0], s1 = ei[ar1];
    const int d0 = ei[NE + ar0], d1 = ei[NE + ar1];

    const float* pS0 = nf + (size_t)s0 * 64;
    const float* pS1 = nf + (size_t)s1 * 64;
    const float* pD0 = nf + (size_t)d0 * 64;
    const float* pD1 = nf + (size_t)d1 * 64;
    const float* pE0 = ef + (size_t)ar0 * 64;
    const float* pE1 = ef + (size_t)ar1 * 64;
    const int o0 = hi * 8, o1 = 32 + hi * 8;

    f32x4 acc[2][8];
#pragma unroll
    for (int i = 0; i < 2; ++i)
#pragma unroll
        for (int j = 0; j < 8; ++j)
#pragma unroll
            for (int q = 0; q < 4; ++q) acc[i][j][q] = 0.0f;

#define KSTEP(PTR0, PTR1, OFF, K0)                                              \
    {                                                                           \
        f32x4 x0l = *(const f32x4*)((PTR0) + (OFF));                            \
        f32x4 x0h = *(const f32x4*)((PTR0) + (OFF) + 4);                        \
        f32x4 x1l = *(const f32x4*)((PTR1) + (OFF));                            \
        f32x4 x1h = *(const f32x4*)((PTR1) + (OFF) + 4);                        \
        s16x8 fa0 = cvt8(x0l, x0h), fa1 = cvt8(x1l, x1h);                       \
        _Pragma("unroll")                                                       \
        for (int ct = 0; ct < 8; ++ct) {                                        \
            s16x8 b = *(const s16x8*)(w1t + (ct * 16 + lo) * 192 + (K0) + hi * 8); \
            acc[0][ct] = __builtin_amdgcn_mfma_f32_16x16x32_bf16(fa0, b, acc[0][ct], 0, 0, 0); \
            acc[1][ct] = __builtin_amdgcn_mfma_f32_16x16x32_bf16(fa1, b, acc[1][ct], 0, 0, 0); \
        }                                                                       \
    }

    KSTEP(pS0, pS1, o0, 0);      // k   0..31 : nf[src] 0..31
    KSTEP(pS0, pS1, o1, 32);     // k  32..63 : nf[src] 32..63
    KSTEP(pD0, pD1, o0, 64);     // k  64..95 : nf[dst] 0..31
    KSTEP(pD0, pD1, o1, 96);     // k  96..127: nf[dst] 32..63
    KSTEP(pE0, pE1, o0, 128);    // k 128..159: ef 0..31
    KSTEP(pE0, pE1, o1, 160);    // k 160..191: ef 32..63
#undef KSTEP

    // bias + tanh GELU -> h_lds (bf16), certified C/D mapping
#pragma unroll
    for (int ct = 0; ct < 8; ++ct) {
        const int col = ct * 16 + lo;
        const float bb = b1[col];
#pragma unroll
        for (int rt = 0; rt < 2; ++rt)
#pragma unroll
            for (int r = 0; r < 4; ++r) {
                float x = acc[rt][ct][r] + bb;
                h_lds[wave * 32 + rt * 16 + hi * 4 + r][col] = f2bf(gelu_fast(x));
            }
    }
    __syncthreads();

    // ---- GEMM2: [128 x 128] @ [128 x 64], MFMA, certified mappings ----
    f32x4 acc2[2][4];
#pragma unroll
    for (int i = 0; i < 2; ++i)
#pragma unroll
        for (int j = 0; j < 4; ++j)
#pragma unroll
            for (int q = 0; q < 4; ++q) acc2[i][j][q] = 0.0f;
#pragma unroll
    for (int ks = 0; ks < 4; ++ks) {
        const int k0 = ks * 32 + hi * 8;
        s16x8 a0 = *(const s16x8*)&h_lds[wave * 32 + lo][k0];
        s16x8 a1 = *(const s16x8*)&h_lds[wave * 32 + 16 + lo][k0];
#pragma unroll
        for (int ct = 0; ct < 4; ++ct) {
            s16x8 b = *(const s16x8*)(w2t + (ct * 16 + lo) * 128 + k0);
            acc2[0][ct] = __builtin_amdgcn_mfma_f32_16x16x32_bf16(a0, b, acc2[0][ct], 0, 0, 0);
            acc2[1][ct] = __builtin_amdgcn_mfma_f32_16x16x32_bf16(a1, b, acc2[1][ct], 0, 0, 0);
        }
    }
    __syncthreads();                          // all h reads done before aliasing overwrite

    // write update u to LDS with the certified C/D mapping (alias h_lds as f32)
    float (*u_lds)[64] = (float (*)[64])h_lds;   // 128*64*4 = 32768 B, exact alias
#pragma unroll
    for (int ct = 0; ct < 4; ++ct)
#pragma unroll
        for (int rt = 0; rt < 2; ++rt)
#pragma unroll
            for (int r = 0; r < 4; ++r)
                u_lds[wave * 32 + rt * 16 + hi * 4 + r][ct * 16 + lo] = acc2[rt][ct][r];
    __syncthreads();

    // ---- certified SERIAL epilogue: lane = output column (0..63) ----
    const float b2v = b2[lane], gmv = gamma[lane], btv = beta[lane];
#pragma unroll 4
    for (int e = 0; e < 32; ++e) {
        const int er   = wave * 32 + e;              // block-local row
        const int erow = blockIdx.x * 128 + er;      // global edge row
        float o = u_lds[er][lane] + b2v + ef[(size_t)erow * 64 + lane];
        float s = o, s2 = o * o;
#pragma unroll
        for (int m = 1; m < 64; m <<= 1) { s += __shfl_xor(s, m); s2 += __shfl_xor(s2, m); }
        const float mean = s * 0.015625f;
        const float var  = s2 * 0.015625f - mean * mean;
        const float rs   = rsqrtf(var + 1e-5f);
        const float out  = (o - mean) * rs * gmv + btv;
        eout[(size_t)erow * 64 + lane] = out;
        const int dn = ei[NE + erow];
        if (SLOTS) {
            if (lane == 0) {
                int idx = atomicAdd(&cnti[dn], 1);
                slots[(size_t)dn * 64 + (idx & 63)] = (u32)erow;  // P(idx>63)~1e-55
            }
        } else {
            atomicAdd(&agg[(size_t)dn * 64 + lane], out);
            if (lane == 0) atomicAdd(&cnti[dn], 1);
        }
    }
}

// ---- node kernel: certified f32 VALU; aggregation input templated ----
template<bool SLOTS>
__global__ __launch_bounds__(256) void node_valu(
    const float* __restrict__ nf,
    const float* __restrict__ w1, const float* __restrict__ b1,   // [128][128], [128]
    const float* __restrict__ w2, const float* __restrict__ b2,   // [128][64],  [64]
    const float* __restrict__ gamma, const float* __restrict__ beta,
    const float* __restrict__ agg, const int* __restrict__ cnti,
    const u32* __restrict__ slots, const float* __restrict__ eout,
    float* __restrict__ nout)
{
    __shared__ float xs[4][128];
    __shared__ float hs[4][128];
    const int wave = threadIdx.x >> 6, lane = threadIdx.x & 63;
    const int n = blockIdx.x * 4 + wave;         // grid covers exactly NN
    if (n >= NN) return;                          // whole-wave exit; no __syncthreads here

    const int m = cnti[n];
    xs[wave][lane] = nf[(size_t)n * 64 + lane];
    if (SLOTS) {
        const int mm = min(m, 64);
        float a = 0.0f;
        for (int i = 0; i < mm; ++i) {
            const u32 eid = slots[(size_t)n * 64 + i];       // wave-uniform
            a += eout[(size_t)eid * 64 + lane];              // coalesced 256B
        }
        xs[wave][64 + lane] = a / fmaxf((float)m, 1.0f);
    } else {
        xs[wave][64 + lane] = agg[(size_t)n * 64 + lane] / fmaxf((float)m, 1.0f);
    }

    float a0 = b1[lane], a1 = b1[64 + lane];
#pragma unroll 8
    for (int k = 0; k < 128; ++k) {
        const float xv = xs[wave][k];            // LDS broadcast
        a0 += xv * w1[k * 128 + lane];
        a1 += xv * w1[k * 128 + 64 + lane];
    }
    hs[wave][lane]      = gelu_exact(a0);
    hs[wave][64 + lane] = gelu_exact(a1);

    float o = b2[lane];
#pragma unroll 8
    for (int k = 0; k < 128; ++k)
        o += hs[wave][k] * w2[k * 64 + lane];
    o += nf[(size_t)n * 64 + lane];              // residual

    float s = o, s2 = o * o;
#pragma unroll
    for (int m2 = 1; m2 < 64; m2 <<= 1) { s += __shfl_xor(s, m2); s2 += __shfl_xor(s2, m2); }
    const float mean = s * 0.015625f;
    const float var  = s2 * 0.015625f - mean * mean;
    const float rs   = rsqrtf(var + 1e-5f);
    nout[(size_t)n * 64 + lane] = (o - mean) * rs * gamma[lane] + beta[lane];
}

extern "C" void kernel_launch(void* const* d_in, const int* in_sizes, int n_in,
                              void* d_out, int out_size, void* d_ws, size_t ws_size,
                              hipStream_t stream)
{
    const float* nf  = (const float*)d_in[0];
    const int*   ei  = (const int*)d_in[1];
    const float* ef  = (const float*)d_in[2];
    const float* ew1 = (const float*)d_in[3];
    const float* eb1 = (const float*)d_in[4];
    const float* ew2 = (const float*)d_in[5];
    const float* eb2 = (const float*)d_in[6];
    const float* nw1 = (const float*)d_in[7];
    const float* nb1 = (const float*)d_in[8];
    const float* nw2 = (const float*)d_in[9];
    const float* nb2 = (const float*)d_in[10];
    const float* eg  = (const float*)d_in[11];
    const float* ebt = (const float*)d_in[12];
    const float* ng  = (const float*)d_in[13];
    const float* nbt = (const float*)d_in[14];

    float* node_out = (float*)d_out;
    float* edge_out = node_out + (size_t)NN * 64;
    char*  ws   = (char*)d_ws;
    int*   cnti = (int*)(ws);               // 50000*4 = 200000 B
    short* ew1t = (short*)(ws + 200704);    // 128*192*2 = 49152 B
    short* ew2t = (short*)(ws + 249856);    // 64*128*2  = 16384 B
    u32*   slots = (u32*)(ws + 266240);     // 50000*64*4 = 12.8 MB
    float* agg  = node_out;                 // fallback path only

    const bool use_slots = ws_size >= (size_t)266240 + (size_t)NN * 64 * 4;

    hipMemsetAsync(cnti, 0, (size_t)NN * 4, stream);
    prep_e<<<128, 256, 0, stream>>>(ew1, ew2, ew1t, ew2t);
    if (use_slots) {
        edge_k<true><<<NE / 128, 256, 0, stream>>>(nf, ei, ef, ew1t, eb1, ew2t, eb2,
                                                   eg, ebt, edge_out, agg, cnti, slots);
        node_valu<true><<<NN / 4, 256, 0, stream>>>(nf, nw1, nb1, nw2, nb2, ng, nbt,
                                                    agg, cnti, slots, edge_out, node_out);
    } else {
        hipMemsetAsync(agg, 0, (size_t)NN * 64 * 4, stream);
        edge_k<false><<<NE / 128, 256, 0, stream>>>(nf, ei, ef, ew1t, eb1, ew2t, eb2,
                                                    eg, ebt, edge_out, agg, cnti, slots);
        node_valu<false><<<NN / 4, 256, 0, stream>>>(nf, nw1, nb1, nw2, nb2, ng, nbt,
                                                     agg, cnti, slots, edge_out, node_out);
    }
}

// Round 10
// 782.885 us; speedup vs baseline: 1.0591x; 1.0591x over previous
//
#include <hip/hip_runtime.h>
#include <math.h>

#define NN 50000
#define NE 800000

typedef float f32x4 __attribute__((ext_vector_type(4)));
typedef short s16x8 __attribute__((ext_vector_type(8)));
typedef unsigned int u32;

__device__ __forceinline__ short f2bf(float f) {
    union { float f; u32 u; } v; v.f = f;
    u32 u = v.u;
    u += 0x7FFF + ((u >> 16) & 1);   // round-to-nearest-even
    return (short)(u >> 16);
}

__device__ __forceinline__ s16x8 cvt8(f32x4 a, f32x4 b) {
    s16x8 r;
    r[0] = f2bf(a[0]); r[1] = f2bf(a[1]); r[2] = f2bf(a[2]); r[3] = f2bf(a[3]);
    r[4] = f2bf(b[0]); r[5] = f2bf(b[1]); r[6] = f2bf(b[2]); r[7] = f2bf(b[3]);
    return r;
}

__device__ __forceinline__ float gelu_exact(float x) {
    return 0.5f * x * (1.0f + erff(x * 0.70710678118654752f));
}

// tanh-form GELU (certified r8): max dev vs erf-GELU ~3e-3 on h -> <2e-3 on out.
__device__ __forceinline__ float gelu_fast(float x) {
    const float z = 1.5957691216f * x * (1.0f + 0.044715f * x * x);
    return x * __builtin_amdgcn_rcpf(1.0f + __expf(-z));
}

// ---- prep: transpose-convert edge weights to bf16 [col][k] (r8 exact) ----
__global__ __launch_bounds__(256) void prep_e(
    const float* __restrict__ ew1, const float* __restrict__ ew2,
    short* __restrict__ ew1t, short* __restrict__ ew2t)
{
    int idx = blockIdx.x * 256 + threadIdx.x;
    if (idx < 24576) {                       // e_w1 [192][128] -> [128][192]
        int k = idx >> 7, c = idx & 127;
        ew1t[c * 192 + k] = f2bf(ew1[idx]);
    } else if (idx < 32768) {                // e_w2 [128][64] -> [64][128]
        int i = idx - 24576; int k = i >> 6, c = i & 63;
        ew2t[c * 128 + k] = f2bf(ew2[i]);
    }
}

// ---- edge kernel: r8 certified dataflow, occupancy-doubled ----
// Round-10 deltas (one theory: latency-bound, TLP-starved):
//  (1) 16 edges/wave (acc[8], single row-group) -> VGPR ~60, launch_bounds
//      (256,8) pins <=64 VGPR => 8 waves/SIMD (2x TLP), epilogue 16 iters.
//  (2) all __syncthreads removed: every LDS access is within the wave's own
//      16-row stripe (verified per access); same-wave LDS RAW is lgkmcnt-
//      ordered by the compiler (node_valu-certified mechanism).
//  (3) h_lds [64][136] (+8 pad) kills the 16-way ds_read_b128 conflict;
//      17408 B/block -> 8 blocks/CU = 139 KB LDS, within 160 KB.
__global__ __launch_bounds__(256, 8) void edge_k(
    const float* __restrict__ nf, const int* __restrict__ ei,
    const float* __restrict__ ef,
    const short* __restrict__ w1t, const float* __restrict__ b1,
    const short* __restrict__ w2t, const float* __restrict__ b2,
    const float* __restrict__ gamma, const float* __restrict__ beta,
    float* __restrict__ eout, float* __restrict__ agg, float* __restrict__ cnt)
{
    __shared__ short h_lds[64][136];         // 17408 B; aliased float[64][68]
    const int tid  = threadIdx.x;
    const int wave = tid >> 6, lane = tid & 63;
    const int lo = lane & 15, hi = lane >> 4;
    const int eb = blockIdx.x * 64 + wave * 16;

    const int ar0 = eb + lo;
    const int s0 = ei[ar0];
    const int d0 = ei[NE + ar0];

    const float* pS0 = nf + (size_t)s0 * 64;
    const float* pD0 = nf + (size_t)d0 * 64;
    const float* pE0 = ef + (size_t)ar0 * 64;
    const int o0 = hi * 8, o1 = 32 + hi * 8;

    f32x4 acc[8];
#pragma unroll
    for (int j = 0; j < 8; ++j)
#pragma unroll
        for (int q = 0; q < 4; ++q) acc[j][q] = 0.0f;

#define KSTEP(PTR0, OFF, K0)                                                    \
    {                                                                           \
        f32x4 x0l = *(const f32x4*)((PTR0) + (OFF));                            \
        f32x4 x0h = *(const f32x4*)((PTR0) + (OFF) + 4);                        \
        s16x8 fa0 = cvt8(x0l, x0h);                                             \
        _Pragma("unroll")                                                       \
        for (int ct = 0; ct < 8; ++ct) {                                        \
            s16x8 b = *(const s16x8*)(w1t + (ct * 16 + lo) * 192 + (K0) + hi * 8); \
            acc[ct] = __builtin_amdgcn_mfma_f32_16x16x32_bf16(fa0, b, acc[ct], 0, 0, 0); \
        }                                                                       \
    }

    KSTEP(pS0, o0, 0);      // k   0..31 : nf[src] 0..31
    KSTEP(pS0, o1, 32);     // k  32..63 : nf[src] 32..63
    KSTEP(pD0, o0, 64);     // k  64..95 : nf[dst] 0..31
    KSTEP(pD0, o1, 96);     // k  96..127: nf[dst] 32..63
    KSTEP(pE0, o0, 128);    // k 128..159: ef 0..31
    KSTEP(pE0, o1, 160);    // k 160..191: ef 32..63
#undef KSTEP

    // bias + tanh GELU -> h_lds (bf16), certified C/D mapping (row-group dropped)
#pragma unroll
    for (int ct = 0; ct < 8; ++ct) {
        const int col = ct * 16 + lo;
        const float bb = b1[col];
#pragma unroll
        for (int r = 0; r < 4; ++r) {
            float x = acc[ct][r] + bb;
            h_lds[wave * 16 + hi * 4 + r][col] = f2bf(gelu_fast(x));
        }
    }
    // no barrier: all LDS traffic below stays within this wave's 16-row stripe

    // ---- GEMM2: [16 x 128] @ [128 x 64] per wave, certified mappings ----
    f32x4 acc2[4];
#pragma unroll
    for (int j = 0; j < 4; ++j)
#pragma unroll
        for (int q = 0; q < 4; ++q) acc2[j][q] = 0.0f;
#pragma unroll
    for (int ks = 0; ks < 4; ++ks) {
        const int k0 = ks * 32 + hi * 8;
        s16x8 a0 = *(const s16x8*)&h_lds[wave * 16 + lo][k0];
#pragma unroll
        for (int ct = 0; ct < 4; ++ct) {
            s16x8 b = *(const s16x8*)(w2t + (ct * 16 + lo) * 128 + k0);
            acc2[ct] = __builtin_amdgcn_mfma_f32_16x16x32_bf16(a0, b, acc2[ct], 0, 0, 0);
        }
    }

    // write update u to LDS with the certified C/D mapping (alias h_lds as f32)
    float (*u_lds)[68] = (float (*)[68])h_lds;   // 64*68*4 = 17408 B, exact alias
#pragma unroll
    for (int ct = 0; ct < 4; ++ct)
#pragma unroll
        for (int r = 0; r < 4; ++r)
            u_lds[wave * 16 + hi * 4 + r][ct * 16 + lo] = acc2[ct][r];

    // ---- certified SERIAL epilogue: lane = output column (0..63), 16 iters ----
    const float b2v = b2[lane], gmv = gamma[lane], btv = beta[lane];
#pragma unroll 4
    for (int e = 0; e < 16; ++e) {
        const int er   = wave * 16 + e;              // block-local row
        const int erow = blockIdx.x * 64 + er;       // global edge row
        float o = u_lds[er][lane] + b2v + ef[(size_t)erow * 64 + lane];
        float s = o, s2 = o * o;
#pragma unroll
        for (int m = 1; m < 64; m <<= 1) { s += __shfl_xor(s, m); s2 += __shfl_xor(s2, m); }
        const float mean = s * 0.015625f;
        const float var  = s2 * 0.015625f - mean * mean;
        const float rs   = rsqrtf(var + 1e-5f);
        const float out  = (o - mean) * rs * gmv + btv;
        eout[(size_t)erow * 64 + lane] = out;
        const int dn = ei[NE + erow];
        atomicAdd(&agg[(size_t)dn * 64 + lane], out);
        if (lane == 0) atomicAdd(&cnt[dn], 1.0f);
    }
}

// ---- node kernel: r8 certified form, verbatim ----
__global__ __launch_bounds__(256) void node_valu(
    const float* __restrict__ nf,
    const float* __restrict__ w1, const float* __restrict__ b1,   // [128][128], [128]
    const float* __restrict__ w2, const float* __restrict__ b2,   // [128][64],  [64]
    const float* __restrict__ gamma, const float* __restrict__ beta,
    const float* __restrict__ agg, const float* __restrict__ cnt,
    float* __restrict__ nout)
{
    __shared__ float xs[4][128];
    __shared__ float hs[4][128];
    const int wave = threadIdx.x >> 6, lane = threadIdx.x & 63;
    const int n = blockIdx.x * 4 + wave;         // grid covers exactly NN
    if (n >= NN) return;                          // whole-wave exit; no __syncthreads here

    const float ic = 1.0f / fmaxf(cnt[n], 1.0f);
    xs[wave][lane]      = nf[(size_t)n * 64 + lane];
    xs[wave][64 + lane] = agg[(size_t)n * 64 + lane] * ic;

    float a0 = b1[lane], a1 = b1[64 + lane];
#pragma unroll 8
    for (int k = 0; k < 128; ++k) {
        const float xv = xs[wave][k];            // LDS broadcast
        a0 += xv * w1[k * 128 + lane];
        a1 += xv * w1[k * 128 + 64 + lane];
    }
    hs[wave][lane]      = gelu_exact(a0);
    hs[wave][64 + lane] = gelu_exact(a1);

    float o = b2[lane];
#pragma unroll 8
    for (int k = 0; k < 128; ++k)
        o += hs[wave][k] * w2[k * 64 + lane];
    o += nf[(size_t)n * 64 + lane];              // residual

    float s = o, s2 = o * o;
#pragma unroll
    for (int m = 1; m < 64; m <<= 1) { s += __shfl_xor(s, m); s2 += __shfl_xor(s2, m); }
    const float mean = s * 0.015625f;
    const float var  = s2 * 0.015625f - mean * mean;
    const float rs   = rsqrtf(var + 1e-5f);
    nout[(size_t)n * 64 + lane] = (o - mean) * rs * gamma[lane] + beta[lane];
}

extern "C" void kernel_launch(void* const* d_in, const int* in_sizes, int n_in,
                              void* d_out, int out_size, void* d_ws, size_t ws_size,
                              hipStream_t stream)
{
    const float* nf  = (const float*)d_in[0];
    const int*   ei  = (const int*)d_in[1];
    const float* ef  = (const float*)d_in[2];
    const float* ew1 = (const float*)d_in[3];
    const float* eb1 = (const float*)d_in[4];
    const float* ew2 = (const float*)d_in[5];
    const float* eb2 = (const float*)d_in[6];
    const float* nw1 = (const float*)d_in[7];
    const float* nb1 = (const float*)d_in[8];
    const float* nw2 = (const float*)d_in[9];
    const float* nb2 = (const float*)d_in[10];
    const float* eg  = (const float*)d_in[11];
    const float* ebt = (const float*)d_in[12];
    const float* ng  = (const float*)d_in[13];
    const float* nbt = (const float*)d_in[14];

    float* node_out = (float*)d_out;
    float* edge_out = node_out + (size_t)NN * 64;
    char*  ws   = (char*)d_ws;
    float* cnt  = (float*)(ws);             // 50000*4 = 200000 B
    short* ew1t = (short*)(ws + 200704);    // 128*192*2 = 49152 B
    short* ew2t = (short*)(ws + 249856);    // 64*128*2  = 16384 B
    float* agg  = node_out;                 // reuse node_out region as agg accumulator

    hipMemsetAsync(agg, 0, (size_t)NN * 64 * 4, stream);
    hipMemsetAsync(cnt, 0, (size_t)NN * 4, stream);
    prep_e<<<128, 256, 0, stream>>>(ew1, ew2, ew1t, ew2t);
    edge_k<<<NE / 64, 256, 0, stream>>>(nf, ei, ef, ew1t, eb1, ew2t, eb2, eg, ebt,
                                        edge_out, agg, cnt);
    node_valu<<<NN / 4, 256, 0, stream>>>(nf, nw1, nb1, nw2, nb2, ng, nbt,
                                          agg, cnt, node_out);
}

// Round 11
// 670.410 us; speedup vs baseline: 1.2368x; 1.1678x over previous
//
#include <hip/hip_runtime.h>
#include <math.h>

#define NN 50000
#define NE 800000

typedef float f32x4 __attribute__((ext_vector_type(4)));
typedef short s16x8 __attribute__((ext_vector_type(8)));
typedef short s16x4 __attribute__((ext_vector_type(4)));
typedef unsigned int u32;

__device__ __forceinline__ short f2bf(float f) {
    union { float f; u32 u; } v; v.f = f;
    u32 u = v.u;
    u += 0x7FFF + ((u >> 16) & 1);   // round-to-nearest-even
    return (short)(u >> 16);
}

__device__ __forceinline__ float u2f(u32 u) {
    union { u32 u; float f; } v; v.u = u; return v.f;
}

__device__ __forceinline__ s16x8 cvt8(f32x4 a, f32x4 b) {
    s16x8 r;
    r[0] = f2bf(a[0]); r[1] = f2bf(a[1]); r[2] = f2bf(a[2]); r[3] = f2bf(a[3]);
    r[4] = f2bf(b[0]); r[5] = f2bf(b[1]); r[6] = f2bf(b[2]); r[7] = f2bf(b[3]);
    return r;
}

__device__ __forceinline__ float gelu_exact(float x) {
    return 0.5f * x * (1.0f + erff(x * 0.70710678118654752f));
}

// tanh-form GELU (certified r8): max dev vs erf-GELU ~3e-3 on h -> <2e-3 on out.
__device__ __forceinline__ float gelu_fast(float x) {
    const float z = 1.5957691216f * x * (1.0f + 0.044715f * x * x);
    return x * __builtin_amdgcn_rcpf(1.0f + __expf(-z));
}

// ---- prep: nf -> bf16 copy (flat) + transpose-convert edge weights ----
__global__ __launch_bounds__(256) void prep_e(
    const float* __restrict__ nf, const float* __restrict__ ew1,
    const float* __restrict__ ew2,
    short* __restrict__ nfh, short* __restrict__ ew1t, short* __restrict__ ew2t)
{
    int idx = blockIdx.x * 256 + threadIdx.x;
    if (idx < NN * 64) nfh[idx] = f2bf(nf[idx]);   // row-major copy, no transpose
    if (idx < 24576) {                       // e_w1 [192][128] -> [128][192]
        int k = idx >> 7, c = idx & 127;
        ew1t[c * 192 + k] = f2bf(ew1[idx]);
    } else if (idx < 32768) {                // e_w2 [128][64] -> [64][128]
        int i = idx - 24576; int k = i >> 6, c = i & 63;
        ew2t[c * 128 + k] = f2bf(ew2[i]);
    }
}

// ---- edge kernel: r10 structure + traffic reduction ----
// Round-11 deltas (one theory: memory-fabric congestion):
//  (1) nf gathered as bf16 from nfh (half gather bytes, no cvt VALU);
//  (2) ef bf16 row stashed to ef_lds during its KSTEPs; epilogue residual
//      reads LDS -> the 205 MB global ef re-read disappears;
//  (3) LDS 26624 B -> 6 blocks/CU (~75% occupancy), below the 8-block
//      L2-thrash regime r10 exposed.
__global__ __launch_bounds__(256, 6) void edge_k(
    const short* __restrict__ nfh, const int* __restrict__ ei,
    const float* __restrict__ ef,
    const short* __restrict__ w1t, const float* __restrict__ b1,
    const short* __restrict__ w2t, const float* __restrict__ b2,
    const float* __restrict__ gamma, const float* __restrict__ beta,
    float* __restrict__ eout, float* __restrict__ agg, float* __restrict__ cnt)
{
    __shared__ short h_lds[64][136];         // 17408 B; aliased float[64][68]
    __shared__ short ef_lds[64][72];         // 9216 B; bf16 ef rows (144 B stride, 8B-aligned)
    const int tid  = threadIdx.x;
    const int wave = tid >> 6, lane = tid & 63;
    const int lo = lane & 15, hi = lane >> 4;
    const int eb = blockIdx.x * 64 + wave * 16;

    const int ar0 = eb + lo;
    const int s0 = ei[ar0];
    const int d0 = ei[NE + ar0];

    const short* pS0 = nfh + (size_t)s0 * 64;
    const short* pD0 = nfh + (size_t)d0 * 64;
    const float* pE0 = ef + (size_t)ar0 * 64;
    const int o0 = hi * 8, o1 = 32 + hi * 8;

    f32x4 acc[8];
#pragma unroll
    for (int j = 0; j < 8; ++j)
#pragma unroll
        for (int q = 0; q < 4; ++q) acc[j][q] = 0.0f;

    // nf segments: direct bf16 gather (16 B/lane)
#define KSTEP_H(PTR, OFF, K0)                                                   \
    {                                                                           \
        s16x8 fa0 = *(const s16x8*)((PTR) + (OFF));                             \
        _Pragma("unroll")                                                       \
        for (int ct = 0; ct < 8; ++ct) {                                        \
            s16x8 b = *(const s16x8*)(w1t + (ct * 16 + lo) * 192 + (K0) + hi * 8); \
            acc[ct] = __builtin_amdgcn_mfma_f32_16x16x32_bf16(fa0, b, acc[ct], 0, 0, 0); \
        }                                                                       \
    }
    // ef segments: f32 load + cvt + STASH bf16 row to ef_lds (two 8B writes)
#define KSTEP_E(OFF, K0, KO)                                                    \
    {                                                                           \
        f32x4 x0l = *(const f32x4*)(pE0 + (OFF));                               \
        f32x4 x0h = *(const f32x4*)(pE0 + (OFF) + 4);                           \
        s16x8 fa0 = cvt8(x0l, x0h);                                             \
        s16x4 flo, fhi;                                                         \
        flo[0]=fa0[0]; flo[1]=fa0[1]; flo[2]=fa0[2]; flo[3]=fa0[3];             \
        fhi[0]=fa0[4]; fhi[1]=fa0[5]; fhi[2]=fa0[6]; fhi[3]=fa0[7];             \
        *(s16x4*)&ef_lds[wave * 16 + lo][(KO) + hi * 8]     = flo;              \
        *(s16x4*)&ef_lds[wave * 16 + lo][(KO) + hi * 8 + 4] = fhi;              \
        _Pragma("unroll")                                                       \
        for (int ct = 0; ct < 8; ++ct) {                                        \
            s16x8 b = *(const s16x8*)(w1t + (ct * 16 + lo) * 192 + (K0) + hi * 8); \
            acc[ct] = __builtin_amdgcn_mfma_f32_16x16x32_bf16(fa0, b, acc[ct], 0, 0, 0); \
        }                                                                       \
    }

    KSTEP_H(pS0, o0, 0);      // k   0..31 : nf[src] 0..31
    KSTEP_H(pS0, o1, 32);     // k  32..63 : nf[src] 32..63
    KSTEP_H(pD0, o0, 64);     // k  64..95 : nf[dst] 0..31
    KSTEP_H(pD0, o1, 96);     // k  96..127: nf[dst] 32..63
    KSTEP_E(o0, 128, 0);      // k 128..159: ef 0..31  (+stash)
    KSTEP_E(o1, 160, 32);     // k 160..191: ef 32..63 (+stash)
#undef KSTEP_H
#undef KSTEP_E

    // bias + tanh GELU -> h_lds (bf16), certified C/D mapping
#pragma unroll
    for (int ct = 0; ct < 8; ++ct) {
        const int col = ct * 16 + lo;
        const float bb = b1[col];
#pragma unroll
        for (int r = 0; r < 4; ++r) {
            float x = acc[ct][r] + bb;
            h_lds[wave * 16 + hi * 4 + r][col] = f2bf(gelu_fast(x));
        }
    }
    // no barrier: all LDS traffic stays within this wave's 16-row stripe

    // ---- GEMM2: [16 x 128] @ [128 x 64] per wave, certified mappings ----
    f32x4 acc2[4];
#pragma unroll
    for (int j = 0; j < 4; ++j)
#pragma unroll
        for (int q = 0; q < 4; ++q) acc2[j][q] = 0.0f;
#pragma unroll
    for (int ks = 0; ks < 4; ++ks) {
        const int k0 = ks * 32 + hi * 8;
        s16x8 a0 = *(const s16x8*)&h_lds[wave * 16 + lo][k0];
#pragma unroll
        for (int ct = 0; ct < 4; ++ct) {
            s16x8 b = *(const s16x8*)(w2t + (ct * 16 + lo) * 128 + k0);
            acc2[ct] = __builtin_amdgcn_mfma_f32_16x16x32_bf16(a0, b, acc2[ct], 0, 0, 0);
        }
    }

    // write update u to LDS with the certified C/D mapping (alias h_lds as f32)
    float (*u_lds)[68] = (float (*)[68])h_lds;   // 64*68*4 = 17408 B, exact alias
#pragma unroll
    for (int ct = 0; ct < 4; ++ct)
#pragma unroll
        for (int r = 0; r < 4; ++r)
            u_lds[wave * 16 + hi * 4 + r][ct * 16 + lo] = acc2[ct][r];

    // ---- certified SERIAL epilogue: lane = output column; residual from LDS ----
    const float b2v = b2[lane], gmv = gamma[lane], btv = beta[lane];
#pragma unroll 4
    for (int e = 0; e < 16; ++e) {
        const int er   = wave * 16 + e;              // block-local row
        const int erow = blockIdx.x * 64 + er;       // global edge row
        const float efv = u2f(((u32)(unsigned short)ef_lds[er][lane]) << 16);
        float o = u_lds[er][lane] + b2v + efv;
        float s = o, s2 = o * o;
#pragma unroll
        for (int m = 1; m < 64; m <<= 1) { s += __shfl_xor(s, m); s2 += __shfl_xor(s2, m); }
        const float mean = s * 0.015625f;
        const float var  = s2 * 0.015625f - mean * mean;
        const float rs   = rsqrtf(var + 1e-5f);
        const float out  = (o - mean) * rs * gmv + btv;
        eout[(size_t)erow * 64 + lane] = out;
        const int dn = ei[NE + erow];
        atomicAdd(&agg[(size_t)dn * 64 + lane], out);
        if (lane == 0) atomicAdd(&cnt[dn], 1.0f);
    }
}

// ---- node kernel: r8 certified form, verbatim ----
__global__ __launch_bounds__(256) void node_valu(
    const float* __restrict__ nf,
    const float* __restrict__ w1, const float* __restrict__ b1,   // [128][128], [128]
    const float* __restrict__ w2, const float* __restrict__ b2,   // [128][64],  [64]
    const float* __restrict__ gamma, const float* __restrict__ beta,
    const float* __restrict__ agg, const float* __restrict__ cnt,
    float* __restrict__ nout)
{
    __shared__ float xs[4][128];
    __shared__ float hs[4][128];
    const int wave = threadIdx.x >> 6, lane = threadIdx.x & 63;
    const int n = blockIdx.x * 4 + wave;         // grid covers exactly NN
    if (n >= NN) return;                          // whole-wave exit; no __syncthreads here

    const float ic = 1.0f / fmaxf(cnt[n], 1.0f);
    xs[wave][lane]      = nf[(size_t)n * 64 + lane];
    xs[wave][64 + lane] = agg[(size_t)n * 64 + lane] * ic;

    float a0 = b1[lane], a1 = b1[64 + lane];
#pragma unroll 8
    for (int k = 0; k < 128; ++k) {
        const float xv = xs[wave][k];            // LDS broadcast
        a0 += xv * w1[k * 128 + lane];
        a1 += xv * w1[k * 128 + 64 + lane];
    }
    hs[wave][lane]      = gelu_exact(a0);
    hs[wave][64 + lane] = gelu_exact(a1);

    float o = b2[lane];
#pragma unroll 8
    for (int k = 0; k < 128; ++k)
        o += hs[wave][k] * w2[k * 64 + lane];
    o += nf[(size_t)n * 64 + lane];              // residual

    float s = o, s2 = o * o;
#pragma unroll
    for (int m = 1; m < 64; m <<= 1) { s += __shfl_xor(s, m); s2 += __shfl_xor(s2, m); }
    const float mean = s * 0.015625f;
    const float var  = s2 * 0.015625f - mean * mean;
    const float rs   = rsqrtf(var + 1e-5f);
    nout[(size_t)n * 64 + lane] = (o - mean) * rs * gamma[lane] + beta[lane];
}

extern "C" void kernel_launch(void* const* d_in, const int* in_sizes, int n_in,
                              void* d_out, int out_size, void* d_ws, size_t ws_size,
                              hipStream_t stream)
{
    const float* nf  = (const float*)d_in[0];
    const int*   ei  = (const int*)d_in[1];
    const float* ef  = (const float*)d_in[2];
    const float* ew1 = (const float*)d_in[3];
    const float* eb1 = (const float*)d_in[4];
    const float* ew2 = (const float*)d_in[5];
    const float* eb2 = (const float*)d_in[6];
    const float* nw1 = (const float*)d_in[7];
    const float* nb1 = (const float*)d_in[8];
    const float* nw2 = (const float*)d_in[9];
    const float* nb2 = (const float*)d_in[10];
    const float* eg  = (const float*)d_in[11];
    const float* ebt = (const float*)d_in[12];
    const float* ng  = (const float*)d_in[13];
    const float* nbt = (const float*)d_in[14];

    float* node_out = (float*)d_out;
    float* edge_out = node_out + (size_t)NN * 64;
    char*  ws   = (char*)d_ws;
    float* cnt  = (float*)(ws);             // 50000*4 = 200000 B
    short* ew1t = (short*)(ws + 200704);    // 128*192*2 = 49152 B
    short* ew2t = (short*)(ws + 249856);    // 64*128*2  = 16384 B
    short* nfh  = (short*)(ws + 266240);    // 50000*64*2 = 6.4 MB
    float* agg  = node_out;                 // reuse node_out region as agg accumulator

    hipMemsetAsync(agg, 0, (size_t)NN * 64 * 4, stream);
    hipMemsetAsync(cnt, 0, (size_t)NN * 4, stream);
    prep_e<<<(NN * 64 + 255) / 256, 256, 0, stream>>>(nf, ew1, ew2, nfh, ew1t, ew2t);
    edge_k<<<NE / 64, 256, 0, stream>>>(nfh, ei, ef, ew1t, eb1, ew2t, eb2, eg, ebt,
                                        edge_out, agg, cnt);
    node_valu<<<NN / 4, 256, 0, stream>>>(nf, nw1, nb1, nw2, nb2, ng, nbt,
                                          agg, cnt, node_out);
}